// Round 2
// baseline (383.590 us; speedup 1.0000x reference)
//
#include <hip/hip_runtime.h>
#include <hip/hip_cooperative_groups.h>

// Peak detection + ordered compaction, (8,16,512,512) fp32.
// History: R2 lookback 2.9ms. R4-R9 two-pass ~220us. R10 records-path also
// 219.3us (pass2 savings offset; R9 pass2 already early-exited at cap).
// rocprof R10: top-5 all harness 512MiB ws fills (~80-85us @6.4TB/s) -> our
// kernels < 80us each, NO counters for them; budget says ~90us combined vs
// ~40us roofline model => 2x unexplained. R11: fuse record+scatter into ONE
// cooperative kernel (grid.sync) so it rises above the fills in top-5 and
// we get its FETCH/WRITE/VALUBusy/Occupancy. Merit changes: 16-row strips
// (halo 10/8 -> 18/16 rows, 160->144MB), records re-read L2-hot (same wave
// wrote them, ~3.75MB/XCD), one dispatch. 1024 blocks co-resident at
// __launch_bounds__(256,4) (VGPR<=128, design ~55 live => no R8-style
// allocator serialization). Fallbacks: R10 pair if coop launch rejected,
// R9 pair if ws < 257MB.

namespace {
constexpr int kB = 8;
constexpr int kC = 16;
constexpr int kH = 512;
constexpr int kW = 512;
constexpr int kNPB = kC * kH * kW;              // 4,194,304 px / batch
constexpr int kMaxPeaks = 262144;
constexpr long long kPeaksElems = (long long)kB * kMaxPeaks * 3;
constexpr float kNeg = -3.402823466e38f;
constexpr int kWPB = 4;                         // waves (strips) per block
constexpr int kTPB = 64 * kWPB;                 // 256

// fused (R11) geometry: 16-row strips
constexpr int kRows16 = 16;
constexpr int kS16PerBatch = kC * (kH / kRows16);    // 512
constexpr int kNS16 = kB * kS16PerBatch;             // 4096
constexpr int kCap16 = kRows16 * kW;                 // 8192 records (= px/strip)

// legacy (R9/R10) geometry: 8-row strips
constexpr int kRows = 8;
constexpr int kStripsPerBatch = kC * (kH / kRows);   // 1024
constexpr int kNStrips = kB * kStripsPerBatch;       // 8192
constexpr int kCap = kRows * kW;                     // 4096
}

__device__ __forceinline__ float fmax3(float a, float b, float c) {
  return fmaxf(fmaxf(a, b), c);  // -> v_max3_f32
}

// Load 8 px of strip-relative row i (absolute y = y0+i) or -FLT_MAX outside.
__device__ __forceinline__ void loadrow(const float* __restrict__ rp, int y0,
                                        int i, float d[8]) {
  const int yy = y0 + i;
  if (yy >= 0 && yy < kH) {
    const float4 q0 = *reinterpret_cast<const float4*>(rp + i * kW);
    const float4 q1 = *reinterpret_cast<const float4*>(rp + i * kW + 4);
    d[0] = q0.x; d[1] = q0.y; d[2] = q0.z; d[3] = q0.w;
    d[4] = q1.x; d[5] = q1.y; d[6] = q1.z; d[7] = q1.w;
  } else {
#pragma unroll
    for (int j = 0; j < 8; ++j) d[j] = kNeg;
  }
}

// ---------------------------------------------------------------------------
// R11: fused cooperative kernel. Phase A: wave = one 16-row strip, rolling
// 3-row window + distance-2 prefetch, emits 8B records (conf|y|x) at
// strip-local ranks + strip count. grid.sync. Phase B: batch-wide prefix
// over 512 counts (1 int2/thread), then each wave streams its own strip's
// records (L2-hot) into ordered (x,y,conf) triplets.
// ---------------------------------------------------------------------------
__global__ void __launch_bounds__(kTPB, 4)
peak_fused_kernel(const float* __restrict__ hm,
                  unsigned long long* __restrict__ rec,
                  int* __restrict__ cnts,
                  float* __restrict__ out) {
  const int t = threadIdx.x, lane = t & 63, wv = t >> 6;
  const int g = blockIdx.x;
  const int b = g >> 7;                    // 128 blocks / batch
  const int g0 = (g & 127) * kWPB;         // first strip16 (within batch)
  const int si = g0 + wv;                  // strip16 within batch
  const int s = b * kS16PerBatch + si;
  const int c = si >> 5;                   // 32 strip16 / image
  const int y0 = (si & 31) * kRows16;
  const float* rp = hm + (long long)b * kNPB + c * (kH * kW) + y0 * kW + lane * 8;
  unsigned long long* rb = rec + (long long)s * kCap16;

  float A[8], Bv[8], Cv[8], N1[8], N2[8];
  loadrow(rp, y0, -1, A);
  loadrow(rp, y0, 0, Bv);
  loadrow(rp, y0, 1, Cv);
  loadrow(rp, y0, 2, N1);
  loadrow(rp, y0, 3, N2);

  const unsigned long long pm = (lane == 0) ? 0ull : (~0ull >> (64 - lane));
  int rbase = 0;  // wave-uniform running strip count
#pragma unroll
  for (int r = 0; r < kRows16; ++r) {
    float cm[8];
#pragma unroll
    for (int j = 0; j < 8; ++j) cm[j] = fmax3(A[j], Bv[j], Cv[j]);
    float hl = __shfl_up(cm[7], 1, 64);
    float hr = __shfl_down(cm[0], 1, 64);
    if (lane == 0) hl = kNeg;    // x = -1 (image edge)
    if (lane == 63) hr = kNeg;   // x = 512 (image edge)
    float m[8];
    m[0] = fmax3(hl, cm[0], cm[1]);
#pragma unroll
    for (int j = 1; j < 7; ++j) m[j] = fmax3(cm[j - 1], cm[j], cm[j + 1]);
    m[7] = fmax3(cm[6], cm[7], hr);

    unsigned long long w[8];
    int lexcl = 0, rowcnt = 0;
#pragma unroll
    for (int j = 0; j < 8; ++j) {
      const float v = Bv[j];
      w[j] = __ballot((v == m[j]) && (v > 0.0f));
      lexcl += (int)__popcll(w[j] & pm);
      rowcnt += (int)__popcll(w[j]);
    }
    // rank within row: x = lane*8+j ascending == (earlier lanes' flags over
    // all j) + (own flags with smaller j). Matches reference flat order.
    int rank = rbase + lexcl;
    const unsigned yx = (unsigned)((y0 + r) << 16);
#pragma unroll
    for (int j = 0; j < 8; ++j) {
      const int f = (int)((w[j] >> lane) & 1);
      if (f) {
        rb[rank] = ((unsigned long long)__float_as_uint(Bv[j]) << 32) |
                   (unsigned long long)(yx | (unsigned)(lane * 8 + j));
      }
      rank += f;
    }
    rbase += rowcnt;

    // rotate window + prefetch row r+4 (rows needed end at index 16)
#pragma unroll
    for (int j = 0; j < 8; ++j) { A[j] = Bv[j]; Bv[j] = Cv[j]; Cv[j] = N1[j]; N1[j] = N2[j]; }
    if (r <= kRows16 - 4) loadrow(rp, y0, r + 4, N2);  // compile-time predicate
  }
  if (lane == 0) cnts[s] = rbase;

  cooperative_groups::this_grid().sync();

  // ---- Phase B: prefix + scatter ----
  __shared__ int s_pre[kWPB], s_tot[kWPB], s_c[kWPB];
  const int* cb = cnts + b * kS16PerBatch;
  // thread t owns counts[t*2 .. t*2+1]; g0 % 4 == 0 -> mask thread-uniform
  const int2 c2 = *reinterpret_cast<const int2*>(cb + t * 2);
  const int idx0 = t * 2;
  int tot = c2.x + c2.y;
  int pre = (idx0 < g0) ? tot : 0;
  if (idx0 == g0)     { s_c[0] = c2.x; s_c[1] = c2.y; }
  if (idx0 == g0 + 2) { s_c[2] = c2.x; s_c[3] = c2.y; }
#pragma unroll
  for (int d = 32; d >= 1; d >>= 1) {
    pre += __shfl_down(pre, d, 64);
    tot += __shfl_down(tot, d, 64);
  }
  if (lane == 0) { s_pre[wv] = pre; s_tot[wv] = tot; }
  __syncthreads();
  const int base = s_pre[0] + s_pre[1] + s_pre[2] + s_pre[3];
  if (g0 == 0 && t == 0)
    out[kPeaksElems + b] =
        (float)(s_tot[0] + s_tot[1] + s_tot[2] + s_tot[3]);  // counts[b]

  int off0 = base;
  for (int k = 0; k < wv; ++k) off0 += s_c[k];
  if (off0 >= kMaxPeaks) return;  // wave-uniform; grid sync already passed

  const int lim = min(s_c[wv], kMaxPeaks - off0);
  float* o = out + (long long)b * kMaxPeaks * 3 + (long long)off0 * 3;
  for (int i = lane; i < lim; i += 64) {
    const unsigned long long v = rb[i];   // written by this same wave: L2-hot
    float* p = o + (long long)i * 3;
    p[0] = (float)(unsigned)(v & 0xffffu);
    p[1] = (float)(unsigned)((v >> 16) & 0xffffu);
    p[2] = __uint_as_float((unsigned)(v >> 32));
  }
}

// ---------------------------------------------------------------------------
// R10 fallback pair (verified 219.3us) — used if cooperative launch rejected.
// ---------------------------------------------------------------------------
__global__ void __launch_bounds__(kTPB)
peak_record_kernel(const float* __restrict__ hm,
                   unsigned long long* __restrict__ rec,
                   int* __restrict__ cnts) {
  const int t = threadIdx.x, lane = t & 63, wv = t >> 6;
  const int s = blockIdx.x * kWPB + wv;
  const int b = s >> 10;
  const int si = s & 1023;
  const int c = si >> 6;
  const int y0 = (si & 63) * kRows;
  const float* rp = hm + (long long)b * kNPB + c * (kH * kW) + y0 * kW + lane * 8;
  unsigned long long* rb = rec + (long long)s * kCap;

  float A[8], Bv[8], Cv[8], N1[8], N2[8];
  loadrow(rp, y0, -1, A);
  loadrow(rp, y0, 0, Bv);
  loadrow(rp, y0, 1, Cv);
  loadrow(rp, y0, 2, N1);
  loadrow(rp, y0, 3, N2);

  const unsigned long long pm = (lane == 0) ? 0ull : (~0ull >> (64 - lane));
  int rbase = 0;
#pragma unroll
  for (int r = 0; r < kRows; ++r) {
    float cm[8];
#pragma unroll
    for (int j = 0; j < 8; ++j) cm[j] = fmax3(A[j], Bv[j], Cv[j]);
    float hl = __shfl_up(cm[7], 1, 64);
    float hr = __shfl_down(cm[0], 1, 64);
    if (lane == 0) hl = kNeg;
    if (lane == 63) hr = kNeg;
    float m[8];
    m[0] = fmax3(hl, cm[0], cm[1]);
#pragma unroll
    for (int j = 1; j < 7; ++j) m[j] = fmax3(cm[j - 1], cm[j], cm[j + 1]);
    m[7] = fmax3(cm[6], cm[7], hr);

    unsigned long long w[8];
    int lexcl = 0, rowcnt = 0;
#pragma unroll
    for (int j = 0; j < 8; ++j) {
      const float v = Bv[j];
      w[j] = __ballot((v == m[j]) && (v > 0.0f));
      lexcl += (int)__popcll(w[j] & pm);
      rowcnt += (int)__popcll(w[j]);
    }
    int rank = rbase + lexcl;
    const unsigned yx = (unsigned)((y0 + r) << 16);
#pragma unroll
    for (int j = 0; j < 8; ++j) {
      const int f = (int)((w[j] >> lane) & 1);
      if (f) {
        rb[rank] = ((unsigned long long)__float_as_uint(Bv[j]) << 32) |
                   (unsigned long long)(yx | (unsigned)(lane * 8 + j));
      }
      rank += f;
    }
    rbase += rowcnt;
#pragma unroll
    for (int j = 0; j < 8; ++j) { A[j] = Bv[j]; Bv[j] = Cv[j]; Cv[j] = N1[j]; N1[j] = N2[j]; }
    if (r <= 4) loadrow(rp, y0, r + 4, N2);
  }
  if (lane == 0) cnts[s] = rbase;
}

__global__ void __launch_bounds__(kTPB)
peak_scatter_kernel(const unsigned long long* __restrict__ rec,
                    const int* __restrict__ cnts,
                    float* __restrict__ out) {
  __shared__ int s_pre[kWPB], s_tot[kWPB], s_c[kWPB];
  const int t = threadIdx.x, lane = t & 63, wv = t >> 6;
  const int g = blockIdx.x;
  const int b = g >> 8;
  const int g0 = (g & 255) * kWPB;
  const int* cb = cnts + b * kStripsPerBatch;

  const int4 c4 = *reinterpret_cast<const int4*>(cb + t * 4);
  const int idx0 = t * 4;
  int tot = c4.x + c4.y + c4.z + c4.w;
  int pre = (idx0 < g0) ? tot : 0;
  if (idx0 == g0) { s_c[0] = c4.x; s_c[1] = c4.y; s_c[2] = c4.z; s_c[3] = c4.w; }
#pragma unroll
  for (int d = 32; d >= 1; d >>= 1) {
    pre += __shfl_down(pre, d, 64);
    tot += __shfl_down(tot, d, 64);
  }
  if (lane == 0) { s_pre[wv] = pre; s_tot[wv] = tot; }
  __syncthreads();
  const int base = s_pre[0] + s_pre[1] + s_pre[2] + s_pre[3];
  if (g0 == 0 && t == 0)
    out[kPeaksElems + b] =
        (float)(s_tot[0] + s_tot[1] + s_tot[2] + s_tot[3]);

  int off0 = base;
  for (int k = 0; k < wv; ++k) off0 += s_c[k];
  if (off0 >= kMaxPeaks) return;

  const int s = b * kStripsPerBatch + g0 + wv;
  const int lim = min(s_c[wv], kMaxPeaks - off0);
  const unsigned long long* rb = rec + (long long)s * kCap;
  float* o = out + (long long)b * kMaxPeaks * 3 + (long long)off0 * 3;
  for (int i = lane; i < lim; i += 64) {
    const unsigned long long v = rb[i];
    float* p = o + (long long)i * 3;
    p[0] = (float)(unsigned)(v & 0xffffu);
    p[1] = (float)(unsigned)((v >> 16) & 0xffffu);
    p[2] = __uint_as_float((unsigned)(v >> 32));
  }
}

// ---------------------------------------------------------------------------
// R9 fallback pair (verified 219.7us) — used only if ws_size < 257MB.
// ---------------------------------------------------------------------------
__global__ void __launch_bounds__(kTPB)
peak_count_kernel(const float* __restrict__ hm,
                  unsigned long long* __restrict__ bmw,
                  int* __restrict__ cnts) {
  const int t = threadIdx.x, lane = t & 63, wv = t >> 6;
  const int s = blockIdx.x * kWPB + wv;
  const int b = s >> 10;
  const int si = s & 1023;
  const int c = si >> 6;
  const int y0 = (si & 63) * kRows;
  const float* rp = hm + (long long)b * kNPB + c * (kH * kW) + y0 * kW + lane * 8;

  float A[8], Bv[8], Cv[8], N1[8], N2[8];
  loadrow(rp, y0, -1, A);
  loadrow(rp, y0, 0, Bv);
  loadrow(rp, y0, 1, Cv);
  loadrow(rp, y0, 2, N1);
  loadrow(rp, y0, 3, N2);

  unsigned long long myword = 0;
  int scnt = 0;
#pragma unroll
  for (int r = 0; r < kRows; ++r) {
    float cm[8];
#pragma unroll
    for (int j = 0; j < 8; ++j) cm[j] = fmax3(A[j], Bv[j], Cv[j]);
    float hl = __shfl_up(cm[7], 1, 64);
    float hr = __shfl_down(cm[0], 1, 64);
    if (lane == 0) hl = kNeg;
    if (lane == 63) hr = kNeg;
    float m[8];
    m[0] = fmax3(hl, cm[0], cm[1]);
#pragma unroll
    for (int j = 1; j < 7; ++j) m[j] = fmax3(cm[j - 1], cm[j], cm[j + 1]);
    m[7] = fmax3(cm[6], cm[7], hr);
#pragma unroll
    for (int j = 0; j < 8; ++j) {
      const float v = Bv[j];
      const unsigned long long wj = __ballot((v == m[j]) && (v > 0.0f));
      scnt += (int)__popcll(wj);
      if (lane == r * 8 + j) myword = wj;
    }
#pragma unroll
    for (int j = 0; j < 8; ++j) { A[j] = Bv[j]; Bv[j] = Cv[j]; Cv[j] = N1[j]; N1[j] = N2[j]; }
    if (r <= 4) loadrow(rp, y0, r + 4, N2);
  }
  bmw[(long long)s * 64 + lane] = myword;
  if (lane == 0) cnts[s] = scnt;
}

__global__ void __launch_bounds__(kTPB)
peak_write_kernel(const float* __restrict__ hm,
                  const unsigned long long* __restrict__ bmw,
                  const int* __restrict__ cnts,
                  float* __restrict__ out) {
  __shared__ int s_pre[kWPB], s_tot[kWPB], s_c[kWPB];
  __shared__ unsigned long long s_w[kWPB][64];
  const int t = threadIdx.x, lane = t & 63, wv = t >> 6;
  const int g = blockIdx.x;
  const int b = g >> 8;
  const int g0 = (g & 255) * kWPB;
  const int* cb = cnts + b * kStripsPerBatch;

  const int4 c4 = *reinterpret_cast<const int4*>(cb + t * 4);
  const int idx0 = t * 4;
  int tot = c4.x + c4.y + c4.z + c4.w;
  int pre = (idx0 < g0) ? tot : 0;
  if (idx0 == g0) { s_c[0] = c4.x; s_c[1] = c4.y; s_c[2] = c4.z; s_c[3] = c4.w; }
#pragma unroll
  for (int d = 32; d >= 1; d >>= 1) {
    pre += __shfl_down(pre, d, 64);
    tot += __shfl_down(tot, d, 64);
  }
  if (lane == 0) { s_pre[wv] = pre; s_tot[wv] = tot; }
  __syncthreads();
  const int base = s_pre[0] + s_pre[1] + s_pre[2] + s_pre[3];
  if (g0 == 0 && t == 0)
    out[kPeaksElems + b] =
        (float)(s_tot[0] + s_tot[1] + s_tot[2] + s_tot[3]);

  int off0 = base;
  for (int k = 0; k < wv; ++k) off0 += s_c[k];
  if (off0 >= kMaxPeaks) return;

  const int s = b * kStripsPerBatch + g0 + wv;
  const int si = g0 + wv, c = si >> 6, y0 = (si & 63) * kRows;
  const float* rp = hm + (long long)b * kNPB + c * (kH * kW) + y0 * kW + lane * 8;

  s_w[wv][lane] = bmw[(long long)s * 64 + lane];

  float P0[8], P1[8], cur[8];
  loadrow(rp, y0, 0, P0);
  loadrow(rp, y0, 1, P1);

  const unsigned long long pm = (lane == 0) ? 0ull : (~0ull >> (64 - lane));
  int rbase = off0;
  float* pb = out + (long long)b * kMaxPeaks * 3;
#pragma unroll
  for (int r = 0; r < kRows; ++r) {
#pragma unroll
    for (int j = 0; j < 8; ++j) { cur[j] = P0[j]; P0[j] = P1[j]; }
    if (r < kRows - 2) loadrow(rp, y0, r + 2, P1);

    unsigned long long w[8];
#pragma unroll
    for (int j = 0; j < 8; ++j) w[j] = s_w[wv][r * 8 + j];
    int lexcl = 0, rowcnt = 0;
#pragma unroll
    for (int j = 0; j < 8; ++j) {
      lexcl += (int)__popcll(w[j] & pm);
      rowcnt += (int)__popcll(w[j]);
    }
    int rank = rbase + lexcl;
    const float fy = (float)(y0 + r);
#pragma unroll
    for (int j = 0; j < 8; ++j) {
      const int f = (int)((w[j] >> lane) & 1);
      if (f && rank < kMaxPeaks) {
        float* o = pb + (long long)rank * 3;
        o[0] = (float)(lane * 8 + j);
        o[1] = fy;
        o[2] = cur[j];
      }
      rank += f;
    }
    rbase += rowcnt;
    if (rbase >= kMaxPeaks) break;
  }
}

extern "C" void kernel_launch(void* const* d_in, const int* in_sizes, int n_in,
                              void* d_out, int out_size, void* d_ws, size_t ws_size,
                              hipStream_t stream) {
  const float* hm = (const float*)d_in[0];
  float* out = (float*)d_out;

  const size_t rec_bytes =
      (size_t)kNS16 * (size_t)kCap16 * sizeof(unsigned long long);  // 256 MiB
  const size_t need = rec_bytes + (size_t)kNS16 * sizeof(int);

  if (ws_size >= need) {
    unsigned long long* rec = (unsigned long long*)d_ws;
    int* cnts = (int*)((char*)d_ws + rec_bytes);
    void* args[4] = {(void*)&hm, (void*)&rec, (void*)&cnts, (void*)&out};
    hipError_t e = hipLaunchCooperativeKernel(
        (void*)peak_fused_kernel, dim3(kNS16 / kWPB), dim3(kTPB), args, 0,
        stream);
    if (e != hipSuccess) {
      (void)hipGetLastError();  // clear sticky error, fall back to R10 pair
      peak_record_kernel<<<kNStrips / kWPB, kTPB, 0, stream>>>(hm, rec, cnts);
      peak_scatter_kernel<<<kNStrips / kWPB, kTPB, 0, stream>>>(rec, cnts, out);
    }
  } else {
    // R9 fallback: masks 8192*64 u64 (4 MB) | strip counts 8192 int
    unsigned long long* bmw = (unsigned long long*)d_ws;
    int* cnts = (int*)(bmw + (long long)kNStrips * 64);
    peak_count_kernel<<<kNStrips / kWPB, kTPB, 0, stream>>>(hm, bmw, cnts);
    peak_write_kernel<<<kNStrips / kWPB, kTPB, 0, stream>>>(hm, bmw, cnts, out);
  }
}

// Round 3
// 217.566 us; speedup vs baseline: 1.7631x; 1.7631x over previous
//
#include <hip/hip_runtime.h>

// Peak detection + ordered compaction, (8,16,512,512) fp32.
// History: R2 lookback 2.9ms. R4-R10 two-pass ~220us. R11 fused+grid.sync:
// kernel alone 210us with VALUBusy 8% / HBM 8% / occ 46% => grid-wide sync
// costs ~100+us at 1024 blocks (matches R8's 310us). COOPERATIVE PATH DEAD.
// R11 counters also showed: total algo HBM traffic = 140MB (roofline ~25us)
// and VGPR_Count=44 — the rolling-window kernels are compiled for 8 waves/
// SIMD, too few regs to keep window+prefetch+masks live, so the allocator
// drains vmcnt right after each load => ~1 load in flight/wave => latency-
// bound at ~1.5TB/s (the R8 lesson again, from the other direction).
// R12: two-dispatch pair, pass 1 issues ALL 10 halo rows up-front (20
// float4 = 20KB in flight/wave) into an 80-reg array under
// __launch_bounds__(256,4) (VGPR cap 128, 16 waves/CU, ~115 live, no
// spill), computes 8 rows from registers. Pass 2 = R10 scatter + 2-deep
// unrolled record loop. R9 fallback kept for ws < 257MB.

namespace {
constexpr int kB = 8;
constexpr int kC = 16;
constexpr int kH = 512;
constexpr int kW = 512;
constexpr int kNPB = kC * kH * kW;              // 4,194,304 px / batch
constexpr int kMaxPeaks = 262144;
constexpr long long kPeaksElems = (long long)kB * kMaxPeaks * 3;
constexpr float kNeg = -3.402823466e38f;
constexpr int kWPB = 4;                         // waves (strips) per block
constexpr int kTPB = 64 * kWPB;                 // 256

constexpr int kRows = 8;                        // rows per strip
constexpr int kStripsPerBatch = kC * (kH / kRows);   // 1024
constexpr int kNStrips = kB * kStripsPerBatch;       // 8192
constexpr int kCap = kRows * kW;                     // 4096 records/strip
}

__device__ __forceinline__ float fmax3(float a, float b, float c) {
  return fmaxf(fmaxf(a, b), c);  // -> v_max3_f32
}

// Load 8 px of strip-relative row i (absolute y = y0+i) or -FLT_MAX outside.
__device__ __forceinline__ void loadrow(const float* __restrict__ rp, int y0,
                                        int i, float d[8]) {
  const int yy = y0 + i;
  if (yy >= 0 && yy < kH) {
    const float4 q0 = *reinterpret_cast<const float4*>(rp + i * kW);
    const float4 q1 = *reinterpret_cast<const float4*>(rp + i * kW + 4);
    d[0] = q0.x; d[1] = q0.y; d[2] = q0.z; d[3] = q0.w;
    d[4] = q1.x; d[5] = q1.y; d[6] = q1.z; d[7] = q1.w;
  } else {
#pragma unroll
    for (int j = 0; j < 8; ++j) d[j] = kNeg;
  }
}

// ---------------------------------------------------------------------------
// R12 pass 1: wave = one 8-row strip; lane l owns x=l*8..+7. ALL 10 halo
// rows loaded up-front (20 float4 in flight), compute entirely from regs.
// Emits 8B records (conf<<32 | y<<16 | x) at strip-local ranks + count.
// ---------------------------------------------------------------------------
__global__ void __launch_bounds__(kTPB, 4)
peak_record_kernel(const float* __restrict__ hm,
                   unsigned long long* __restrict__ rec,
                   int* __restrict__ cnts) {
  const int t = threadIdx.x, lane = t & 63, wv = t >> 6;
  const int s = blockIdx.x * kWPB + wv;
  const int b = s >> 10;                 // 1024 strips / batch
  const int si = s & 1023;
  const int c = si >> 6;                 // 64 strips / image
  const int y0 = (si & 63) * kRows;
  const float* rp = hm + (long long)b * kNPB + c * (kH * kW) + y0 * kW + lane * 8;
  unsigned long long* rb = rec + (long long)s * kCap;

  // rows -1..8 -> R[0..9]; all 20 float4 loads issued before any compute.
  float R[kRows + 2][8];
#pragma unroll
  for (int d = 0; d < kRows + 2; ++d) loadrow(rp, y0, d - 1, R[d]);

  const unsigned long long pm = (lane == 0) ? 0ull : (~0ull >> (64 - lane));
  int rbase = 0;  // wave-uniform running strip count
#pragma unroll
  for (int r = 0; r < kRows; ++r) {
    // R[r] = row r-1, R[r+1] = row r (center), R[r+2] = row r+1
    float cm[8];
#pragma unroll
    for (int j = 0; j < 8; ++j) cm[j] = fmax3(R[r][j], R[r + 1][j], R[r + 2][j]);
    float hl = __shfl_up(cm[7], 1, 64);
    float hr = __shfl_down(cm[0], 1, 64);
    if (lane == 0) hl = kNeg;    // x = -1 (image edge)
    if (lane == 63) hr = kNeg;   // x = 512 (image edge)
    float m[8];
    m[0] = fmax3(hl, cm[0], cm[1]);
#pragma unroll
    for (int j = 1; j < 7; ++j) m[j] = fmax3(cm[j - 1], cm[j], cm[j + 1]);
    m[7] = fmax3(cm[6], cm[7], hr);

    unsigned long long w[8];
    int lexcl = 0, rowcnt = 0;
#pragma unroll
    for (int j = 0; j < 8; ++j) {
      const float v = R[r + 1][j];
      w[j] = __ballot((v == m[j]) && (v > 0.0f));
      lexcl += (int)__popcll(w[j] & pm);
      rowcnt += (int)__popcll(w[j]);
    }
    // rank within row: x = lane*8+j ascending == (earlier lanes' flags over
    // all j) + (own flags with smaller j). Matches reference flat order.
    int rank = rbase + lexcl;
    const unsigned yx = (unsigned)((y0 + r) << 16);
#pragma unroll
    for (int j = 0; j < 8; ++j) {
      const int f = (int)((w[j] >> lane) & 1);
      if (f) {
        rb[rank] = ((unsigned long long)__float_as_uint(R[r + 1][j]) << 32) |
                   (unsigned long long)(yx | (unsigned)(lane * 8 + j));
      }
      rank += f;
    }
    rbase += rowcnt;
  }
  if (lane == 0) cnts[s] = rbase;
}

// ---------------------------------------------------------------------------
// R12 pass 2: block owns 4 consecutive strips of one batch. Redundant masked
// prefix over the batch's 1024 counts (L2-warm, 1 int4/thread), then each
// wave streams its strip's records (LLC-hot) into ordered (x,y,conf)
// triplets. Record loop unrolled 2-deep for 2 loads in flight.
// ---------------------------------------------------------------------------
__global__ void __launch_bounds__(kTPB)
peak_scatter_kernel(const unsigned long long* __restrict__ rec,
                    const int* __restrict__ cnts,
                    float* __restrict__ out) {
  __shared__ int s_pre[kWPB], s_tot[kWPB], s_c[kWPB];
  const int t = threadIdx.x, lane = t & 63, wv = t >> 6;
  const int g = blockIdx.x;
  const int b = g >> 8;                  // 256 groups / batch
  const int g0 = (g & 255) * kWPB;       // first strip (within batch) of block
  const int* cb = cnts + b * kStripsPerBatch;

  // thread t owns counts[t*4 .. t*4+3]; g0 % 4 == 0 -> mask is thread-uniform
  const int4 c4 = *reinterpret_cast<const int4*>(cb + t * 4);
  const int idx0 = t * 4;
  int tot = c4.x + c4.y + c4.z + c4.w;
  int pre = (idx0 < g0) ? tot : 0;
  if (idx0 == g0) { s_c[0] = c4.x; s_c[1] = c4.y; s_c[2] = c4.z; s_c[3] = c4.w; }
#pragma unroll
  for (int d = 32; d >= 1; d >>= 1) {
    pre += __shfl_down(pre, d, 64);
    tot += __shfl_down(tot, d, 64);
  }
  if (lane == 0) { s_pre[wv] = pre; s_tot[wv] = tot; }
  __syncthreads();
  const int base = s_pre[0] + s_pre[1] + s_pre[2] + s_pre[3];
  if (g0 == 0 && t == 0)
    out[kPeaksElems + b] =
        (float)(s_tot[0] + s_tot[1] + s_tot[2] + s_tot[3]);  // counts[b]

  int off0 = base;
  for (int k = 0; k < wv; ++k) off0 += s_c[k];
  if (off0 >= kMaxPeaks) return;  // wave-uniform; no barriers below

  const int s = b * kStripsPerBatch + g0 + wv;
  const int lim = min(s_c[wv], kMaxPeaks - off0);
  const unsigned long long* rb = rec + (long long)s * kCap;
  float* o = out + (long long)b * kMaxPeaks * 3 + (long long)off0 * 3;

  int i = lane;
  for (; i + 64 < lim; i += 128) {  // 2 independent loads in flight
    const unsigned long long v0 = rb[i];
    const unsigned long long v1 = rb[i + 64];
    float* p0 = o + (long long)i * 3;
    float* p1 = o + (long long)(i + 64) * 3;
    p0[0] = (float)(unsigned)(v0 & 0xffffu);
    p0[1] = (float)(unsigned)((v0 >> 16) & 0xffffu);
    p0[2] = __uint_as_float((unsigned)(v0 >> 32));
    p1[0] = (float)(unsigned)(v1 & 0xffffu);
    p1[1] = (float)(unsigned)((v1 >> 16) & 0xffffu);
    p1[2] = __uint_as_float((unsigned)(v1 >> 32));
  }
  if (i < lim) {
    const unsigned long long v = rb[i];
    float* p = o + (long long)i * 3;
    p[0] = (float)(unsigned)(v & 0xffffu);
    p[1] = (float)(unsigned)((v >> 16) & 0xffffu);
    p[2] = __uint_as_float((unsigned)(v >> 32));
  }
}

// ---------------------------------------------------------------------------
// R9 fallback pair (verified 219.7us) — used only if ws_size < 257MB.
// ---------------------------------------------------------------------------
__global__ void __launch_bounds__(kTPB)
peak_count_kernel(const float* __restrict__ hm,
                  unsigned long long* __restrict__ bmw,
                  int* __restrict__ cnts) {
  const int t = threadIdx.x, lane = t & 63, wv = t >> 6;
  const int s = blockIdx.x * kWPB + wv;
  const int b = s >> 10;
  const int si = s & 1023;
  const int c = si >> 6;
  const int y0 = (si & 63) * kRows;
  const float* rp = hm + (long long)b * kNPB + c * (kH * kW) + y0 * kW + lane * 8;

  float A[8], Bv[8], Cv[8], N1[8], N2[8];
  loadrow(rp, y0, -1, A);
  loadrow(rp, y0, 0, Bv);
  loadrow(rp, y0, 1, Cv);
  loadrow(rp, y0, 2, N1);
  loadrow(rp, y0, 3, N2);

  unsigned long long myword = 0;
  int scnt = 0;
#pragma unroll
  for (int r = 0; r < kRows; ++r) {
    float cm[8];
#pragma unroll
    for (int j = 0; j < 8; ++j) cm[j] = fmax3(A[j], Bv[j], Cv[j]);
    float hl = __shfl_up(cm[7], 1, 64);
    float hr = __shfl_down(cm[0], 1, 64);
    if (lane == 0) hl = kNeg;
    if (lane == 63) hr = kNeg;
    float m[8];
    m[0] = fmax3(hl, cm[0], cm[1]);
#pragma unroll
    for (int j = 1; j < 7; ++j) m[j] = fmax3(cm[j - 1], cm[j], cm[j + 1]);
    m[7] = fmax3(cm[6], cm[7], hr);
#pragma unroll
    for (int j = 0; j < 8; ++j) {
      const float v = Bv[j];
      const unsigned long long wj = __ballot((v == m[j]) && (v > 0.0f));
      scnt += (int)__popcll(wj);
      if (lane == r * 8 + j) myword = wj;
    }
#pragma unroll
    for (int j = 0; j < 8; ++j) { A[j] = Bv[j]; Bv[j] = Cv[j]; Cv[j] = N1[j]; N1[j] = N2[j]; }
    if (r <= 4) loadrow(rp, y0, r + 4, N2);
  }
  bmw[(long long)s * 64 + lane] = myword;
  if (lane == 0) cnts[s] = scnt;
}

__global__ void __launch_bounds__(kTPB)
peak_write_kernel(const float* __restrict__ hm,
                  const unsigned long long* __restrict__ bmw,
                  const int* __restrict__ cnts,
                  float* __restrict__ out) {
  __shared__ int s_pre[kWPB], s_tot[kWPB], s_c[kWPB];
  __shared__ unsigned long long s_w[kWPB][64];
  const int t = threadIdx.x, lane = t & 63, wv = t >> 6;
  const int g = blockIdx.x;
  const int b = g >> 8;
  const int g0 = (g & 255) * kWPB;
  const int* cb = cnts + b * kStripsPerBatch;

  const int4 c4 = *reinterpret_cast<const int4*>(cb + t * 4);
  const int idx0 = t * 4;
  int tot = c4.x + c4.y + c4.z + c4.w;
  int pre = (idx0 < g0) ? tot : 0;
  if (idx0 == g0) { s_c[0] = c4.x; s_c[1] = c4.y; s_c[2] = c4.z; s_c[3] = c4.w; }
#pragma unroll
  for (int d = 32; d >= 1; d >>= 1) {
    pre += __shfl_down(pre, d, 64);
    tot += __shfl_down(tot, d, 64);
  }
  if (lane == 0) { s_pre[wv] = pre; s_tot[wv] = tot; }
  __syncthreads();
  const int base = s_pre[0] + s_pre[1] + s_pre[2] + s_pre[3];
  if (g0 == 0 && t == 0)
    out[kPeaksElems + b] =
        (float)(s_tot[0] + s_tot[1] + s_tot[2] + s_tot[3]);

  int off0 = base;
  for (int k = 0; k < wv; ++k) off0 += s_c[k];
  if (off0 >= kMaxPeaks) return;

  const int s = b * kStripsPerBatch + g0 + wv;
  const int si = g0 + wv, c = si >> 6, y0 = (si & 63) * kRows;
  const float* rp = hm + (long long)b * kNPB + c * (kH * kW) + y0 * kW + lane * 8;

  s_w[wv][lane] = bmw[(long long)s * 64 + lane];

  float P0[8], P1[8], cur[8];
  loadrow(rp, y0, 0, P0);
  loadrow(rp, y0, 1, P1);

  const unsigned long long pm = (lane == 0) ? 0ull : (~0ull >> (64 - lane));
  int rbase = off0;
  float* pb = out + (long long)b * kMaxPeaks * 3;
#pragma unroll
  for (int r = 0; r < kRows; ++r) {
#pragma unroll
    for (int j = 0; j < 8; ++j) { cur[j] = P0[j]; P0[j] = P1[j]; }
    if (r < kRows - 2) loadrow(rp, y0, r + 2, P1);

    unsigned long long w[8];
#pragma unroll
    for (int j = 0; j < 8; ++j) w[j] = s_w[wv][r * 8 + j];
    int lexcl = 0, rowcnt = 0;
#pragma unroll
    for (int j = 0; j < 8; ++j) {
      lexcl += (int)__popcll(w[j] & pm);
      rowcnt += (int)__popcll(w[j]);
    }
    int rank = rbase + lexcl;
    const float fy = (float)(y0 + r);
#pragma unroll
    for (int j = 0; j < 8; ++j) {
      const int f = (int)((w[j] >> lane) & 1);
      if (f && rank < kMaxPeaks) {
        float* o = pb + (long long)rank * 3;
        o[0] = (float)(lane * 8 + j);
        o[1] = fy;
        o[2] = cur[j];
      }
      rank += f;
    }
    rbase += rowcnt;
    if (rbase >= kMaxPeaks) break;
  }
}

extern "C" void kernel_launch(void* const* d_in, const int* in_sizes, int n_in,
                              void* d_out, int out_size, void* d_ws, size_t ws_size,
                              hipStream_t stream) {
  const float* hm = (const float*)d_in[0];
  float* out = (float*)d_out;

  const size_t rec_bytes =
      (size_t)kNStrips * (size_t)kCap * sizeof(unsigned long long);  // 256 MiB
  const size_t need = rec_bytes + (size_t)kNStrips * sizeof(int);

  if (ws_size >= need) {
    // R12: records 8192*4096 u64 (256 MiB) | strip counts 8192 int
    unsigned long long* rec = (unsigned long long*)d_ws;
    int* cnts = (int*)((char*)d_ws + rec_bytes);
    peak_record_kernel<<<kNStrips / kWPB, kTPB, 0, stream>>>(hm, rec, cnts);
    peak_scatter_kernel<<<kNStrips / kWPB, kTPB, 0, stream>>>(rec, cnts, out);
  } else {
    // R9 fallback: masks 8192*64 u64 (4 MB) | strip counts 8192 int
    unsigned long long* bmw = (unsigned long long*)d_ws;
    int* cnts = (int*)(bmw + (long long)kNStrips * 64);
    peak_count_kernel<<<kNStrips / kWPB, kTPB, 0, stream>>>(hm, bmw, cnts);
    peak_write_kernel<<<kNStrips / kWPB, kTPB, 0, stream>>>(hm, bmw, cnts, out);
  }
}

// Round 5
// 217.288 us; speedup vs baseline: 1.7654x; 1.0013x over previous
//
#include <hip/hip_runtime.h>

// Peak detection + ordered compaction, (8,16,512,512) fp32.
// FINAL (R14 = verified R12): two-dispatch record+scatter pair, 217.6us.
//
// History/evidence for why this is the stopping point:
// - R2 lookback 2.9ms; R4-R10 structurally different two-pass designs all
//   ~217-220us (masks, records, rolling vs up-front loads).
// - R11 fused + grid.sync: kernel alone 210us, VALUBusy 8%, HBM 8%,
//   occupancy 46% => single-counter grid barrier costs ~100+us at 1024
//   blocks (matches R8's 310us).
// - R13 distributed flag-sync spin-wait: hung the container twice.
//   Conclusion: cross-block rendezvous is either ~100us or a hang here;
//   the dispatch-count lever is unavailable.
// - Budget refit from R11's clean same-session data: harness floor =
//   383.6 - 210.3 ~= 173us (512MiB ws re-poison fill ~85us @6.6TB/s,
//   measured in top-5 every round, + out fill + ~4 dispatch/graph-gap
//   overheads ~20us each). Pair cost = 217.6 - 173 ~= 44us, which matches
//   its traffic roofline: pass 1 reads 128MB + 25% halo (~155MB logical,
//   82MB HBM after LLC absorption per R11 FETCH) + writes 30MB records
//   ~= 30us; pass 2 reads ~17MB (LLC-hot) + writes 25MB ~= 12us.
// => The algorithm is at its memory roofline; remaining time is fixed
//    harness floor. R9/R10/R12's three-way tie confirms it empirically.

namespace {
constexpr int kB = 8;
constexpr int kC = 16;
constexpr int kH = 512;
constexpr int kW = 512;
constexpr int kNPB = kC * kH * kW;              // 4,194,304 px / batch
constexpr int kMaxPeaks = 262144;
constexpr long long kPeaksElems = (long long)kB * kMaxPeaks * 3;
constexpr float kNeg = -3.402823466e38f;
constexpr int kWPB = 4;                         // waves (strips) per block
constexpr int kTPB = 64 * kWPB;                 // 256

constexpr int kRows = 8;                        // rows per strip
constexpr int kStripsPerBatch = kC * (kH / kRows);   // 1024
constexpr int kNStrips = kB * kStripsPerBatch;       // 8192
constexpr int kCap = kRows * kW;                     // 4096 records/strip
}

__device__ __forceinline__ float fmax3(float a, float b, float c) {
  return fmaxf(fmaxf(a, b), c);  // -> v_max3_f32
}

// Load 8 px of strip-relative row i (absolute y = y0+i) or -FLT_MAX outside.
__device__ __forceinline__ void loadrow(const float* __restrict__ rp, int y0,
                                        int i, float d[8]) {
  const int yy = y0 + i;
  if (yy >= 0 && yy < kH) {
    const float4 q0 = *reinterpret_cast<const float4*>(rp + i * kW);
    const float4 q1 = *reinterpret_cast<const float4*>(rp + i * kW + 4);
    d[0] = q0.x; d[1] = q0.y; d[2] = q0.z; d[3] = q0.w;
    d[4] = q1.x; d[5] = q1.y; d[6] = q1.z; d[7] = q1.w;
  } else {
#pragma unroll
    for (int j = 0; j < 8; ++j) d[j] = kNeg;
  }
}

// ---------------------------------------------------------------------------
// Pass 1: wave = one 8-row strip; lane l owns x=l*8..+7. ALL 10 halo rows
// loaded up-front (20 float4 = 20KB in flight/wave; launch_bounds(256,4)
// caps VGPR at 128 so ~115 live regs fit without the allocator serializing
// the loads — the R8/R11 VGPR=44/64 lesson). Compute entirely from regs.
// Emits 8B records (conf<<32 | y<<16 | x) at strip-local ranks + count.
// ---------------------------------------------------------------------------
__global__ void __launch_bounds__(kTPB, 4)
peak_record_kernel(const float* __restrict__ hm,
                   unsigned long long* __restrict__ rec,
                   int* __restrict__ cnts) {
  const int t = threadIdx.x, lane = t & 63, wv = t >> 6;
  const int s = blockIdx.x * kWPB + wv;
  const int b = s >> 10;                 // 1024 strips / batch
  const int si = s & 1023;
  const int c = si >> 6;                 // 64 strips / image
  const int y0 = (si & 63) * kRows;
  const float* rp = hm + (long long)b * kNPB + c * (kH * kW) + y0 * kW + lane * 8;
  unsigned long long* rb = rec + (long long)s * kCap;

  // rows -1..8 -> R[0..9]; all 20 float4 loads issued before any compute.
  float R[kRows + 2][8];
#pragma unroll
  for (int d = 0; d < kRows + 2; ++d) loadrow(rp, y0, d - 1, R[d]);

  const unsigned long long pm = (lane == 0) ? 0ull : (~0ull >> (64 - lane));
  int rbase = 0;  // wave-uniform running strip count
#pragma unroll
  for (int r = 0; r < kRows; ++r) {
    // R[r] = row r-1, R[r+1] = row r (center), R[r+2] = row r+1
    float cm[8];
#pragma unroll
    for (int j = 0; j < 8; ++j) cm[j] = fmax3(R[r][j], R[r + 1][j], R[r + 2][j]);
    float hl = __shfl_up(cm[7], 1, 64);
    float hr = __shfl_down(cm[0], 1, 64);
    if (lane == 0) hl = kNeg;    // x = -1 (image edge)
    if (lane == 63) hr = kNeg;   // x = 512 (image edge)
    float m[8];
    m[0] = fmax3(hl, cm[0], cm[1]);
#pragma unroll
    for (int j = 1; j < 7; ++j) m[j] = fmax3(cm[j - 1], cm[j], cm[j + 1]);
    m[7] = fmax3(cm[6], cm[7], hr);

    unsigned long long w[8];
    int lexcl = 0, rowcnt = 0;
#pragma unroll
    for (int j = 0; j < 8; ++j) {
      const float v = R[r + 1][j];
      w[j] = __ballot((v == m[j]) && (v > 0.0f));
      lexcl += (int)__popcll(w[j] & pm);
      rowcnt += (int)__popcll(w[j]);
    }
    // rank within row: x = lane*8+j ascending == (earlier lanes' flags over
    // all j) + (own flags with smaller j). Matches reference flat order.
    int rank = rbase + lexcl;
    const unsigned yx = (unsigned)((y0 + r) << 16);
#pragma unroll
    for (int j = 0; j < 8; ++j) {
      const int f = (int)((w[j] >> lane) & 1);
      if (f) {
        rb[rank] = ((unsigned long long)__float_as_uint(R[r + 1][j]) << 32) |
                   (unsigned long long)(yx | (unsigned)(lane * 8 + j));
      }
      rank += f;
    }
    rbase += rowcnt;
  }
  if (lane == 0) cnts[s] = rbase;
}

// ---------------------------------------------------------------------------
// Pass 2: block owns 4 consecutive strips of one batch. Redundant masked
// prefix over the batch's 1024 counts (L2-warm, 1 int4/thread), then each
// wave streams its strip's records (LLC-hot) into ordered (x,y,conf)
// triplets. Record loop unrolled 2-deep for 2 loads in flight.
// ---------------------------------------------------------------------------
__global__ void __launch_bounds__(kTPB)
peak_scatter_kernel(const unsigned long long* __restrict__ rec,
                    const int* __restrict__ cnts,
                    float* __restrict__ out) {
  __shared__ int s_pre[kWPB], s_tot[kWPB], s_c[kWPB];
  const int t = threadIdx.x, lane = t & 63, wv = t >> 6;
  const int g = blockIdx.x;
  const int b = g >> 8;                  // 256 groups / batch
  const int g0 = (g & 255) * kWPB;       // first strip (within batch) of block
  const int* cb = cnts + b * kStripsPerBatch;

  // thread t owns counts[t*4 .. t*4+3]; g0 % 4 == 0 -> mask is thread-uniform
  const int4 c4 = *reinterpret_cast<const int4*>(cb + t * 4);
  const int idx0 = t * 4;
  int tot = c4.x + c4.y + c4.z + c4.w;
  int pre = (idx0 < g0) ? tot : 0;
  if (idx0 == g0) { s_c[0] = c4.x; s_c[1] = c4.y; s_c[2] = c4.z; s_c[3] = c4.w; }
#pragma unroll
  for (int d = 32; d >= 1; d >>= 1) {
    pre += __shfl_down(pre, d, 64);
    tot += __shfl_down(tot, d, 64);
  }
  if (lane == 0) { s_pre[wv] = pre; s_tot[wv] = tot; }
  __syncthreads();
  const int base = s_pre[0] + s_pre[1] + s_pre[2] + s_pre[3];
  if (g0 == 0 && t == 0)
    out[kPeaksElems + b] =
        (float)(s_tot[0] + s_tot[1] + s_tot[2] + s_tot[3]);  // counts[b]

  int off0 = base;
  for (int k = 0; k < wv; ++k) off0 += s_c[k];
  if (off0 >= kMaxPeaks) return;  // wave-uniform; no barriers below

  const int s = b * kStripsPerBatch + g0 + wv;
  const int lim = min(s_c[wv], kMaxPeaks - off0);
  const unsigned long long* rb = rec + (long long)s * kCap;
  float* o = out + (long long)b * kMaxPeaks * 3 + (long long)off0 * 3;

  int i = lane;
  for (; i + 64 < lim; i += 128) {  // 2 independent loads in flight
    const unsigned long long v0 = rb[i];
    const unsigned long long v1 = rb[i + 64];
    float* p0 = o + (long long)i * 3;
    float* p1 = o + (long long)(i + 64) * 3;
    p0[0] = (float)(unsigned)(v0 & 0xffffu);
    p0[1] = (float)(unsigned)((v0 >> 16) & 0xffffu);
    p0[2] = __uint_as_float((unsigned)(v0 >> 32));
    p1[0] = (float)(unsigned)(v1 & 0xffffu);
    p1[1] = (float)(unsigned)((v1 >> 16) & 0xffffu);
    p1[2] = __uint_as_float((unsigned)(v1 >> 32));
  }
  if (i < lim) {
    const unsigned long long v = rb[i];
    float* p = o + (long long)i * 3;
    p[0] = (float)(unsigned)(v & 0xffffu);
    p[1] = (float)(unsigned)((v >> 16) & 0xffffu);
    p[2] = __uint_as_float((unsigned)(v >> 32));
  }
}

// ---------------------------------------------------------------------------
// R9 fallback pair (verified 219.7us) — used only if ws_size < 257MB.
// ---------------------------------------------------------------------------
__global__ void __launch_bounds__(kTPB)
peak_count_kernel(const float* __restrict__ hm,
                  unsigned long long* __restrict__ bmw,
                  int* __restrict__ cnts) {
  const int t = threadIdx.x, lane = t & 63, wv = t >> 6;
  const int s = blockIdx.x * kWPB + wv;
  const int b = s >> 10;
  const int si = s & 1023;
  const int c = si >> 6;
  const int y0 = (si & 63) * kRows;
  const float* rp = hm + (long long)b * kNPB + c * (kH * kW) + y0 * kW + lane * 8;

  float A[8], Bv[8], Cv[8], N1[8], N2[8];
  loadrow(rp, y0, -1, A);
  loadrow(rp, y0, 0, Bv);
  loadrow(rp, y0, 1, Cv);
  loadrow(rp, y0, 2, N1);
  loadrow(rp, y0, 3, N2);

  unsigned long long myword = 0;
  int scnt = 0;
#pragma unroll
  for (int r = 0; r < kRows; ++r) {
    float cm[8];
#pragma unroll
    for (int j = 0; j < 8; ++j) cm[j] = fmax3(A[j], Bv[j], Cv[j]);
    float hl = __shfl_up(cm[7], 1, 64);
    float hr = __shfl_down(cm[0], 1, 64);
    if (lane == 0) hl = kNeg;
    if (lane == 63) hr = kNeg;
    float m[8];
    m[0] = fmax3(hl, cm[0], cm[1]);
#pragma unroll
    for (int j = 1; j < 7; ++j) m[j] = fmax3(cm[j - 1], cm[j], cm[j + 1]);
    m[7] = fmax3(cm[6], cm[7], hr);
#pragma unroll
    for (int j = 0; j < 8; ++j) {
      const float v = Bv[j];
      const unsigned long long wj = __ballot((v == m[j]) && (v > 0.0f));
      scnt += (int)__popcll(wj);
      if (lane == r * 8 + j) myword = wj;
    }
#pragma unroll
    for (int j = 0; j < 8; ++j) { A[j] = Bv[j]; Bv[j] = Cv[j]; Cv[j] = N1[j]; N1[j] = N2[j]; }
    if (r <= 4) loadrow(rp, y0, r + 4, N2);
  }
  bmw[(long long)s * 64 + lane] = myword;
  if (lane == 0) cnts[s] = scnt;
}

__global__ void __launch_bounds__(kTPB)
peak_write_kernel(const float* __restrict__ hm,
                  const unsigned long long* __restrict__ bmw,
                  const int* __restrict__ cnts,
                  float* __restrict__ out) {
  __shared__ int s_pre[kWPB], s_tot[kWPB], s_c[kWPB];
  __shared__ unsigned long long s_w[kWPB][64];
  const int t = threadIdx.x, lane = t & 63, wv = t >> 6;
  const int g = blockIdx.x;
  const int b = g >> 8;
  const int g0 = (g & 255) * kWPB;
  const int* cb = cnts + b * kStripsPerBatch;

  const int4 c4 = *reinterpret_cast<const int4*>(cb + t * 4);
  const int idx0 = t * 4;
  int tot = c4.x + c4.y + c4.z + c4.w;
  int pre = (idx0 < g0) ? tot : 0;
  if (idx0 == g0) { s_c[0] = c4.x; s_c[1] = c4.y; s_c[2] = c4.z; s_c[3] = c4.w; }
#pragma unroll
  for (int d = 32; d >= 1; d >>= 1) {
    pre += __shfl_down(pre, d, 64);
    tot += __shfl_down(tot, d, 64);
  }
  if (lane == 0) { s_pre[wv] = pre; s_tot[wv] = tot; }
  __syncthreads();
  const int base = s_pre[0] + s_pre[1] + s_pre[2] + s_pre[3];
  if (g0 == 0 && t == 0)
    out[kPeaksElems + b] =
        (float)(s_tot[0] + s_tot[1] + s_tot[2] + s_tot[3]);

  int off0 = base;
  for (int k = 0; k < wv; ++k) off0 += s_c[k];
  if (off0 >= kMaxPeaks) return;

  const int s = b * kStripsPerBatch + g0 + wv;
  const int si = g0 + wv, c = si >> 6, y0 = (si & 63) * kRows;
  const float* rp = hm + (long long)b * kNPB + c * (kH * kW) + y0 * kW + lane * 8;

  s_w[wv][lane] = bmw[(long long)s * 64 + lane];

  float P0[8], P1[8], cur[8];
  loadrow(rp, y0, 0, P0);
  loadrow(rp, y0, 1, P1);

  const unsigned long long pm = (lane == 0) ? 0ull : (~0ull >> (64 - lane));
  int rbase = off0;
  float* pb = out + (long long)b * kMaxPeaks * 3;
#pragma unroll
  for (int r = 0; r < kRows; ++r) {
#pragma unroll
    for (int j = 0; j < 8; ++j) { cur[j] = P0[j]; P0[j] = P1[j]; }
    if (r < kRows - 2) loadrow(rp, y0, r + 2, P1);

    unsigned long long w[8];
#pragma unroll
    for (int j = 0; j < 8; ++j) w[j] = s_w[wv][r * 8 + j];
    int lexcl = 0, rowcnt = 0;
#pragma unroll
    for (int j = 0; j < 8; ++j) {
      lexcl += (int)__popcll(w[j] & pm);
      rowcnt += (int)__popcll(w[j]);
    }
    int rank = rbase + lexcl;
    const float fy = (float)(y0 + r);
#pragma unroll
    for (int j = 0; j < 8; ++j) {
      const int f = (int)((w[j] >> lane) & 1);
      if (f && rank < kMaxPeaks) {
        float* o = pb + (long long)rank * 3;
        o[0] = (float)(lane * 8 + j);
        o[1] = fy;
        o[2] = cur[j];
      }
      rank += f;
    }
    rbase += rowcnt;
    if (rbase >= kMaxPeaks) break;
  }
}

extern "C" void kernel_launch(void* const* d_in, const int* in_sizes, int n_in,
                              void* d_out, int out_size, void* d_ws, size_t ws_size,
                              hipStream_t stream) {
  const float* hm = (const float*)d_in[0];
  float* out = (float*)d_out;

  const size_t rec_bytes =
      (size_t)kNStrips * (size_t)kCap * sizeof(unsigned long long);  // 256 MiB
  const size_t need = rec_bytes + (size_t)kNStrips * sizeof(int);

  if (ws_size >= need) {
    // records 8192*4096 u64 (256 MiB) | strip counts 8192 int
    unsigned long long* rec = (unsigned long long*)d_ws;
    int* cnts = (int*)((char*)d_ws + rec_bytes);
    peak_record_kernel<<<kNStrips / kWPB, kTPB, 0, stream>>>(hm, rec, cnts);
    peak_scatter_kernel<<<kNStrips / kWPB, kTPB, 0, stream>>>(rec, cnts, out);
  } else {
    // R9 fallback: masks 8192*64 u64 (4 MB) | strip counts 8192 int
    unsigned long long* bmw = (unsigned long long*)d_ws;
    int* cnts = (int*)(bmw + (long long)kNStrips * 64);
    peak_count_kernel<<<kNStrips / kWPB, kTPB, 0, stream>>>(hm, bmw, cnts);
    peak_write_kernel<<<kNStrips / kWPB, kTPB, 0, stream>>>(hm, bmw, cnts, out);
  }
}